// Round 1
// baseline (373.766 us; speedup 1.0000x reference)
//
#include <hip/hip_runtime.h>

// B3-spline a-trous UWT, 3 levels, STREAMING formulation.
// x: (16,1024,1024) f32 -> out: (16,4,1024,1024) f32 = [w1,w2,w3,c3].
// One block = 224-col stripe x 64-row band. Three 32-row rolling rings in LDS
// (x, y1, y2; bf16, 256 cols each = 48 KB). Per 8-row chunk: load x rows,
// compute y1 rows (V1+H1), y2 rows (V2+H2), y3+emit (V4+H4 + subtractions).
// Every phase = 8 rows x 32 col-octets = 256 tasks = 1 task/thread.
// Horizontal halo (+-2D cols) comes from neighbor lanes via __shfl (lane = c8,
// 32 c8 per half-wave); edge-lane garbage lands only in cols proven unused.
// Ring slot = (row+128)&31; live spans verified <= 32 rows in all phases.

#define HH 1024
#define WW 1024
#define STRIDE 256   // u16 per ring row
#define EMITW 224    // emitted cols per stripe
#define HSEG 64      // emitted rows per block
#define NCH (HSEG / 8 + 4)  // 4 warm-up + 8 steady chunks

typedef unsigned short u16;
typedef unsigned int u32;
typedef float f4 __attribute__((ext_vector_type(4)));

__device__ __forceinline__ int reflect_i(int g, int n) {
    if (g < 0) g = -g;
    else if (g >= n) g = 2 * n - 2 - g;
    return g;
}
__device__ __forceinline__ float bl(u32 u) { return __uint_as_float(u << 16); }
__device__ __forceinline__ float bh(u32 u) { return __uint_as_float(u & 0xffff0000u); }
__device__ __forceinline__ u32 pack2(float a, float b) {
    u32 ua = __float_as_uint(a); ua += 0x7fff + ((ua >> 16) & 1);
    u32 ub = __float_as_uint(b); ub += 0x7fff + ((ub >> 16) & 1);
    return (ua >> 16) | (ub & 0xffff0000u);
}
__device__ __forceinline__ void unpack8(uint4 v, float* f) {
    f[0] = bl(v.x); f[1] = bh(v.x);
    f[2] = bl(v.y); f[3] = bh(v.y);
    f[4] = bl(v.z); f[5] = bh(v.z);
    f[6] = bl(v.w); f[7] = bh(v.w);
}
__device__ constexpr float K0 = 1.0f / 16.0f;
__device__ constexpr float K1 = 4.0f / 16.0f;
__device__ constexpr float K2 = 6.0f / 16.0f;

__device__ __forceinline__ int rslot(int q) { return (q + 128) & 31; }

// Vertical 5-tap (dilation D) at ring row q over cols [8c8, 8c8+8), then
// horizontal 5-tap using +-2D col halo pulled from lane+-1 via shuffles.
template <int D>
__device__ __forceinline__ void conv_vh(const u16* __restrict__ src, int q, int c8,
                                        int lane, float* h) {
    uint4 tv[5];
#pragma unroll
    for (int k = 0; k < 5; ++k)
        tv[k] = *(const uint4*)(src + rslot(q + (k - 2) * D) * STRIDE + 8 * c8);
    float v8[8];
    {
        float a[8], b[8];
        unpack8(tv[0], a); unpack8(tv[4], b);
#pragma unroll
        for (int c = 0; c < 8; ++c) v8[c] = K0 * (a[c] + b[c]);
        unpack8(tv[1], a); unpack8(tv[3], b);
#pragma unroll
        for (int c = 0; c < 8; ++c) v8[c] += K1 * (a[c] + b[c]);
        unpack8(tv[2], a);
#pragma unroll
        for (int c = 0; c < 8; ++c) v8[c] += K2 * a[c];
    }
    // ext[i] = V[col base + i - 2D], i in [0, 8+4D)
    float ext[8 + 4 * D];
#pragma unroll
    for (int c = 0; c < 8; ++c) ext[2 * D + c] = v8[c];
#pragma unroll
    for (int j = 0; j < 2 * D; ++j) {
        ext[j]             = __shfl(v8[8 - 2 * D + j], lane - 1);
        ext[2 * D + 8 + j] = __shfl(v8[j], lane + 1);
    }
#pragma unroll
    for (int c = 0; c < 8; ++c)
        h[c] = K0 * (ext[c] + ext[c + 4 * D]) + K1 * (ext[c + D] + ext[c + 3 * D])
             + K2 * ext[c + 2 * D];
}

__device__ __forceinline__ void ring_write(u16* dst, int q, int c8, const float* h) {
    uint4 ov;
    ov.x = pack2(h[0], h[1]); ov.y = pack2(h[2], h[3]);
    ov.z = pack2(h[4], h[5]); ov.w = pack2(h[6], h[7]);
    *(uint4*)(dst + rslot(q) * STRIDE + 8 * c8) = ov;
}

__device__ __forceinline__ void nt4(float* p, float a, float b, float c, float d) {
    f4 v; v.x = a; v.y = b; v.z = c; v.w = d;
    __builtin_nontemporal_store(v, (f4*)p);
}

__global__ __launch_bounds__(256, 3) void uwt3_stream(const float* __restrict__ x,
                                                      float* __restrict__ out) {
    __shared__ __align__(16) u16 ring[3][32][STRIDE];  // 48 KB: x, y1, y2 rings
    u16* xr  = &ring[0][0][0];
    u16* y1r = &ring[1][0][0];
    u16* y2r = &ring[2][0][0];
    const int tid = threadIdx.x;
    const int lane = tid & 63;
    const int rowic = 2 * (tid >> 6) + (lane >> 5);  // 0..7: row within chunk
    const int c8 = lane & 31;                        // col octet 0..31
    const int stripe0 = blockIdx.x * EMITW;
    const int R0 = blockIdx.y * HSEG;
    const int bz = blockIdx.z;
    const float* xb = x + (size_t)bz * HH * WW;
    const size_t PL = (size_t)HH * WW;

    for (int t = 0; t < NCH; ++t) {
        const int r = R0 - 32 + 8 * t;  // chunk base (emit rows r..r+7 when t>=4)

        {   // ---- load x rows r+14..r+21 into x ring (f32 -> bf16, reflect) ----
            int q = r + 14 + rowic;
            int gr = reflect_i(q, HH);
            int w0 = stripe0 - 16 + 8 * c8;
            const float* row = xb + (size_t)gr * WW;
            float f[8];
            if (w0 >= 0 && w0 + 7 < WW) {
                float4 a = *(const float4*)(row + w0);
                float4 b = *(const float4*)(row + w0 + 4);
                f[0] = a.x; f[1] = a.y; f[2] = a.z; f[3] = a.w;
                f[4] = b.x; f[5] = b.y; f[6] = b.z; f[7] = b.w;
            } else {
#pragma unroll
                for (int k = 0; k < 8; ++k) f[k] = row[reflect_i(w0 + k, WW)];
            }
            uint4 v;
            v.x = pack2(f[0], f[1]); v.y = pack2(f[2], f[3]);
            v.z = pack2(f[4], f[5]); v.w = pack2(f[6], f[7]);
            *(uint4*)(xr + rslot(q) * STRIDE + 8 * c8) = v;
        }
        __syncthreads();

        if (t >= 1) {  // ---- y1 rows r+12..r+19 (d=1), needs x rows r+10..r+21 ----
            float h[8];
            int q = r + 12 + rowic;
            conv_vh<1>(xr, q, c8, lane, h);
            ring_write(y1r, q, c8, h);
        }
        __syncthreads();

        if (t >= 2) {  // ---- y2 rows r+8..r+15 (d=2), needs y1 rows r+4..r+19 ----
            float h[8];
            int q = r + 8 + rowic;
            conv_vh<2>(y1r, q, c8, lane, h);
            ring_write(y2r, q, c8, h);
        }
        __syncthreads();

        if (t >= 4) {  // ---- y3 rows r..r+7 (d=4, needs y2 r-8..r+15) + emit ----
            int q = r + rowic;
            float h[8];
            conv_vh<4>(y2r, q, c8, lane, h);
            if (c8 >= 2 && c8 < 30) {
                int w = stripe0 + 8 * c8 - 16;
                if (w < WW) {  // last stripe clips to image width
                    float xv[8], a1[8], a2[8];
                    const int so = rslot(q) * STRIDE + 8 * c8;
                    unpack8(*(const uint4*)(xr + so), xv);
                    unpack8(*(const uint4*)(y1r + so), a1);
                    unpack8(*(const uint4*)(y2r + so), a2);
                    size_t b0 = (((size_t)bz * 4) * HH + q) * (size_t)WW + w;
                    nt4(out + b0,              xv[0]-a1[0], xv[1]-a1[1], xv[2]-a1[2], xv[3]-a1[3]);
                    nt4(out + b0 + 4,          xv[4]-a1[4], xv[5]-a1[5], xv[6]-a1[6], xv[7]-a1[7]);
                    nt4(out + b0 + PL,         a1[0]-a2[0], a1[1]-a2[1], a1[2]-a2[2], a1[3]-a2[3]);
                    nt4(out + b0 + PL + 4,     a1[4]-a2[4], a1[5]-a2[5], a1[6]-a2[6], a1[7]-a2[7]);
                    nt4(out + b0 + 2*PL,       a2[0]-h[0],  a2[1]-h[1],  a2[2]-h[2],  a2[3]-h[3]);
                    nt4(out + b0 + 2*PL + 4,   a2[4]-h[4],  a2[5]-h[5],  a2[6]-h[6],  a2[7]-h[7]);
                    nt4(out + b0 + 3*PL,       h[0], h[1], h[2], h[3]);
                    nt4(out + b0 + 3*PL + 4,   h[4], h[5], h[6], h[7]);
                }
            }
        }
        // no trailing barrier: next chunk's x-load writes ring slots of rows
        // r+22..r+29 (== slots of dead rows r-10..r-3), disjoint from every
        // slot read in this emit phase; the barrier after that load fences it.
    }
}

extern "C" void kernel_launch(void* const* d_in, const int* in_sizes, int n_in,
                              void* d_out, int out_size, void* d_ws, size_t ws_size,
                              hipStream_t stream) {
    const float* x = (const float*)d_in[0];
    float* out = (float*)d_out;
    dim3 grid((WW + EMITW - 1) / EMITW, HH / HSEG, 16);  // 5 x 16 x 16 = 1280
    uwt3_stream<<<grid, dim3(256, 1, 1), 0, stream>>>(x, out);
}

// Round 2
// 347.821 us; speedup vs baseline: 1.0746x; 1.0746x over previous
//
#include <hip/hip_runtime.h>

// B3-spline a-trous UWT, 3 levels, streaming v2: register-prefetch + small rings.
// x: (16,1024,1024) f32 -> out: (16,4,1024,1024) f32 = [w1,w2,w3,c3].
// One block = 224-col stripe x 64-row band, marching down in 8-row chunks.
// Rings (bf16, 256 cols): x 16 rows (8KB), y1 16 rows (8KB), y2 32 rows (16KB)
// = 32 KB -> 4 blocks/CU with __launch_bounds__(256,4) (16 waves/CU).
// Chunk t (r = R0-32+8t), 2 barriers:
//   A: ds_write prefetched x rows r+14..r+21           (t<=11)
//   bar1
//   issue global loads rows r+22..r+29 -> regs         (t<=10)  [latency hides
//   B: y1 rows r+12..r+19 (V1+H1 via shfl), emit w1    (1<=t<=11)  under B+CD]
//   bar2
//   C: y2 rows r+8..r+15, emit w2                      (2<=t<=11)
//   D: y3 rows r-8..r-1 (reads y2 <= r+7 only: no C-D dep), emit w3+c3 (t>=5)
// Live spans: x r+10..r+21 (12<=16), y1 r+4..r+19 (16<=16), y2 r-16..r+15
// (24<=32, C writes r+8..r+15 disjoint from D reads r-16..r+7). All slot-
// recycling WAR hazards separated by >=1 barrier; CD->A' boundary touches
// disjoint rings. Emission uses the center vertical tap (ctr) for the
// subtrahend, so no extra LDS reads. Garbage from shfl wrap stays in cols
// <14 / >=242 of the 256-col stripe; emitted cols are [16,240).

#define HH 1024
#define WW 1024
#define STRIDE 256   // u16 per ring row
#define EMITW 224
#define HSEG 64
#define NCH 13

typedef unsigned short u16;
typedef unsigned int u32;
typedef float f4v __attribute__((ext_vector_type(4)));

__device__ __forceinline__ int reflect_i(int g, int n) {
    if (g < 0) g = -g;
    else if (g >= n) g = 2 * n - 2 - g;
    return g;
}
__device__ __forceinline__ float bl(u32 u) { return __uint_as_float(u << 16); }
__device__ __forceinline__ float bh(u32 u) { return __uint_as_float(u & 0xffff0000u); }
__device__ __forceinline__ u32 pack2(float a, float b) {
    u32 ua = __float_as_uint(a); ua += 0x7fff + ((ua >> 16) & 1);
    u32 ub = __float_as_uint(b); ub += 0x7fff + ((ub >> 16) & 1);
    return (ua >> 16) | (ub & 0xffff0000u);
}
__device__ __forceinline__ void unpack8(uint4 v, float* f) {
    f[0] = bl(v.x); f[1] = bh(v.x);
    f[2] = bl(v.y); f[3] = bh(v.y);
    f[4] = bl(v.z); f[5] = bh(v.z);
    f[6] = bl(v.w); f[7] = bh(v.w);
}
__device__ constexpr float K0 = 1.0f / 16.0f;
__device__ constexpr float K1 = 4.0f / 16.0f;
__device__ constexpr float K2 = 6.0f / 16.0f;

// Vertical 5-tap (dilation D) at ring row q, cols [8c8,8c8+8), then horizontal
// 5-tap with +-2D col halo via lane+-1 shuffles. ctr = center vertical tap
// (the level's input value at row q), h = level output.
template <int D, int RMASK>
__device__ __forceinline__ void conv_vh(const u16* __restrict__ src, int q, int c8,
                                        int lane, float* h, float* ctr) {
    uint4 tv[5];
#pragma unroll
    for (int k = 0; k < 5; ++k) {
        int s = (q + (k - 2) * D + 256) & RMASK;
        tv[k] = *(const uint4*)(src + s * STRIDE + 8 * c8);
    }
    float v8[8];
    {
        float a[8], b[8];
        unpack8(tv[0], a); unpack8(tv[4], b);
#pragma unroll
        for (int c = 0; c < 8; ++c) v8[c] = K0 * (a[c] + b[c]);
        unpack8(tv[1], a); unpack8(tv[3], b);
#pragma unroll
        for (int c = 0; c < 8; ++c) v8[c] += K1 * (a[c] + b[c]);
        unpack8(tv[2], ctr);
#pragma unroll
        for (int c = 0; c < 8; ++c) v8[c] += K2 * ctr[c];
    }
    float ext[8 + 4 * D];
#pragma unroll
    for (int c = 0; c < 8; ++c) ext[2 * D + c] = v8[c];
#pragma unroll
    for (int j = 0; j < 2 * D; ++j) {
        ext[j]             = __shfl(v8[8 - 2 * D + j], lane - 1);
        ext[2 * D + 8 + j] = __shfl(v8[j], lane + 1);
    }
#pragma unroll
    for (int c = 0; c < 8; ++c)
        h[c] = K0 * (ext[c] + ext[c + 4 * D]) + K1 * (ext[c + D] + ext[c + 3 * D])
             + K2 * ext[c + 2 * D];
}

__device__ __forceinline__ void ring_write(u16* dst, int slot, int c8, const float* h) {
    uint4 ov;
    ov.x = pack2(h[0], h[1]); ov.y = pack2(h[2], h[3]);
    ov.z = pack2(h[4], h[5]); ov.w = pack2(h[6], h[7]);
    *(uint4*)(dst + slot * STRIDE + 8 * c8) = ov;
}

__device__ __forceinline__ void emit2(float* __restrict__ out, size_t base,
                                      const float* a) {
    f4v v0; v0.x = a[0]; v0.y = a[1]; v0.z = a[2]; v0.w = a[3];
    f4v v1; v1.x = a[4]; v1.y = a[5]; v1.z = a[6]; v1.w = a[7];
    __builtin_nontemporal_store(v0, (f4v*)(out + base));
    __builtin_nontemporal_store(v1, (f4v*)(out + base + 4));
}

__device__ __forceinline__ void load_row(const float* __restrict__ xb, int q,
                                         int w0, float* f) {
    int gr = reflect_i(q, HH);
    const float* row = xb + (size_t)gr * WW;
    if (w0 >= 0 && w0 + 7 < WW) {
        float4 a = *(const float4*)(row + w0);
        float4 b = *(const float4*)(row + w0 + 4);
        f[0] = a.x; f[1] = a.y; f[2] = a.z; f[3] = a.w;
        f[4] = b.x; f[5] = b.y; f[6] = b.z; f[7] = b.w;
    } else {
#pragma unroll
        for (int k = 0; k < 8; ++k) f[k] = row[reflect_i(w0 + k, WW)];
    }
}

__global__ __launch_bounds__(256, 4) void uwt3_stream2(const float* __restrict__ x,
                                                       float* __restrict__ out) {
    __shared__ __align__(16) u16 xr[16 * STRIDE];
    __shared__ __align__(16) u16 y1r[16 * STRIDE];
    __shared__ __align__(16) u16 y2r[32 * STRIDE];
    const int tid = threadIdx.x;
    const int lane = tid & 63;
    const int rowic = 2 * (tid >> 6) + (lane >> 5);  // 0..7
    const int c8 = lane & 31;
    const int stripe0 = blockIdx.x * EMITW;
    const int R0 = blockIdx.y * HSEG;
    const int bz = blockIdx.z;
    const float* xb = x + (size_t)bz * HH * WW;
    const size_t PL = (size_t)HH * WW;
    const int w0 = stripe0 - 16 + 8 * c8;  // load col base == emit col base
    const bool colok = (c8 >= 2 && c8 < 30 && w0 < WW);
    const size_t ob = ((size_t)bz * 4) * PL + w0;  // + plane*PL + q*WW

    float xf[8];
    load_row(xb, R0 - 32 + 14 + rowic, w0, xf);  // prologue: chunk-0 rows

    for (int t = 0; t < NCH; ++t) {
        const int r = R0 - 32 + 8 * t;

        if (t <= 11) {  // ---- A: commit prefetched x rows r+14..r+21 ----
            int q = r + 14 + rowic;
            uint4 v;
            v.x = pack2(xf[0], xf[1]); v.y = pack2(xf[2], xf[3]);
            v.z = pack2(xf[4], xf[5]); v.w = pack2(xf[6], xf[7]);
            *(uint4*)(xr + ((q + 256) & 15) * STRIDE + 8 * c8) = v;
        }
        __syncthreads();

        if (t <= 10)  // ---- issue next chunk's loads (consumed next A) ----
            load_row(xb, r + 22 + rowic, w0, xf);

        if (t >= 1 && t <= 11) {  // ---- B: y1 rows r+12..r+19, emit w1 ----
            int q = r + 12 + rowic;
            float h[8], ctr[8];
            conv_vh<1, 15>(xr, q, c8, lane, h, ctr);
            ring_write(y1r, (q + 256) & 15, c8, h);
            if (colok && (unsigned)(q - R0) < HSEG) {
                float d[8];
#pragma unroll
                for (int i = 0; i < 8; ++i) d[i] = ctr[i] - h[i];
                emit2(out, ob + (size_t)q * WW, d);
            }
        }
        __syncthreads();

        if (t >= 2 && t <= 11) {  // ---- C: y2 rows r+8..r+15, emit w2 ----
            int q = r + 8 + rowic;
            float h[8], ctr[8];
            conv_vh<2, 15>(y1r, q, c8, lane, h, ctr);
            ring_write(y2r, (q + 256) & 31, c8, h);
            if (colok && (unsigned)(q - R0) < HSEG) {
                float d[8];
#pragma unroll
                for (int i = 0; i < 8; ++i) d[i] = ctr[i] - h[i];
                emit2(out, ob + PL + (size_t)q * WW, d);
            }
        }
        if (t >= 5) {  // ---- D: y3 rows r-8..r-1 (prev-chunk y2 only), emit ----
            int q = r - 8 + rowic;
            float h[8], ctr[8];
            conv_vh<4, 31>(y2r, q, c8, lane, h, ctr);
            if (colok && (unsigned)(q - R0) < HSEG) {
                float d[8];
#pragma unroll
                for (int i = 0; i < 8; ++i) d[i] = ctr[i] - h[i];
                emit2(out, ob + 2 * PL + (size_t)q * WW, d);
                emit2(out, ob + 3 * PL + (size_t)q * WW, h);
            }
        }
        // no trailing barrier: next A writes only the x ring; C/D of this
        // chunk touch only y1/y2 rings; B(t) readers of the recycled x slots
        // are fenced by bar2(t).
    }
}

extern "C" void kernel_launch(void* const* d_in, const int* in_sizes, int n_in,
                              void* d_out, int out_size, void* d_ws, size_t ws_size,
                              hipStream_t stream) {
    const float* x = (const float*)d_in[0];
    float* out = (float*)d_out;
    dim3 grid((WW + EMITW - 1) / EMITW, HH / HSEG, 16);  // 5 x 16 x 16 = 1280
    uwt3_stream2<<<grid, dim3(256, 1, 1), 0, stream>>>(x, out);
}